// Round 1
// baseline (1064.285 us; speedup 1.0000x reference)
//
#include <hip/hip_runtime.h>

typedef _Float16 f16;
typedef _Float16 f16x2 __attribute__((ext_vector_type(2)));
typedef _Float16 f16x4 __attribute__((ext_vector_type(4)));
typedef _Float16 f16x8 __attribute__((ext_vector_type(8)));
typedef float f32x4 __attribute__((ext_vector_type(4)));

#define N_NODES 50000
#define N_EDGES 600000

// ---------- async global->LDS, 16B per lane ----------
__device__ __forceinline__ void gl_lds16(const void* g, void* l) {
  __builtin_amdgcn_global_load_lds(
      (__attribute__((address_space(1))) void*)(g),
      (__attribute__((address_space(3))) void*)(l), 16, 0, 0);
}

// ---------- conversions ----------
__global__ void k_f32_to_f16_x4(const float* __restrict__ in, f16* __restrict__ out, long n4) {
  long i = (long)blockIdx.x * 256 + threadIdx.x;
  if (i < n4) {
    float4 v = ((const float4*)in)[i];
    f16x4 o;
    o[0] = (f16)v.x; o[1] = (f16)v.y; o[2] = (f16)v.z; o[3] = (f16)v.w;
    ((f16x4*)out)[i] = o;
  }
}

// Wt[n][k] = W[k][n] (f16), zero-pad k in [K, Kpad)
__global__ void k_wt(const float* __restrict__ W, f16* __restrict__ Wt,
                     int K, int N, int Kpad) {
  int k = blockIdx.x * 256 + threadIdx.x;
  int n = blockIdx.y;
  if (k < Kpad)
    Wt[(size_t)n * Kpad + k] = (k < K) ? (f16)W[(size_t)k * N + n] : (f16)0.f;
}

// ---------- graph build ----------
__global__ void k_deg(const int* __restrict__ dst, int* __restrict__ deg, int E) {
  int e = blockIdx.x * 256 + threadIdx.x;
  if (e < E) atomicAdd(&deg[dst[e]], 1);
}

__global__ void k_dinv(const int* __restrict__ deg, float* __restrict__ dinv, int n) {
  int i = blockIdx.x * 256 + threadIdx.x;
  if (i < n) dinv[i] = rsqrtf((float)(deg[i] + 1));  // +1 self loop
}

// exclusive scan of deg -> rowptr[0..n], single block of 1024
__global__ void k_scan(const int* __restrict__ deg, int* __restrict__ rowptr, int n) {
  __shared__ int wsum[16];
  __shared__ int carry_s;
  int tid = threadIdx.x;
  int lane = tid & 63, w = tid >> 6;
  if (tid == 0) carry_s = 0;
  __syncthreads();
  for (int base = 0; base < n; base += 1024) {
    int i = base + tid;
    int v = (i < n) ? deg[i] : 0;
    int incl = v;
#pragma unroll
    for (int off = 1; off < 64; off <<= 1) {
      int t = __shfl_up(incl, off, 64);
      if (lane >= off) incl += t;
    }
    if (lane == 63) wsum[w] = incl;
    __syncthreads();
    if (tid < 16) {
      int t = wsum[tid];
#pragma unroll
      for (int off = 1; off < 16; off <<= 1) {
        int u = __shfl_up(t, off, 64);
        if (tid >= off) t += u;
      }
      wsum[tid] = t;  // inclusive over waves
    }
    __syncthreads();
    int c = carry_s;
    int wprefix = (w == 0) ? 0 : wsum[w - 1];
    if (i < n) rowptr[i] = c + wprefix + incl - v;
    __syncthreads();
    if (tid == 0) carry_s = c + wsum[15];
    __syncthreads();
  }
  if (threadIdx.x == 0) rowptr[n] = carry_s;
}

__global__ void k_fill(const int* __restrict__ src, const int* __restrict__ dst,
                       const int* __restrict__ rowptr, int* __restrict__ cursor,
                       int* __restrict__ col, float* __restrict__ wnorm,
                       const float* __restrict__ dinv, int E) {
  int e = blockIdx.x * 256 + threadIdx.x;
  if (e < E) {
    int d = dst[e], s = src[e];
    int pos = rowptr[d] + atomicAdd(&cursor[d], 1);
    col[pos] = s;
    wnorm[pos] = dinv[s] * dinv[d];
  }
}

// ---------- GEMM: C[M,N] = A[M,K] * B^T[N,K], f16 in, f16 out ----------
// 128x128 tile, BK=32, 4 waves (2x2 of 64x64), mfma_f32_16x16x32_f16
__global__ __launch_bounds__(256, 2)
void gemm_f16_tn(const f16* __restrict__ A, const f16* __restrict__ B,
                 f16* __restrict__ C, int M, int N, int K,
                 int lda, int ldb, int ldc) {
  __shared__ __align__(16) f16 As[128 * 32];
  __shared__ __align__(16) f16 Bs[128 * 32];
  const int tid = threadIdx.x;
  const int wave = tid >> 6;
  const int lane = tid & 63;
  const int bm = blockIdx.x, bn = blockIdx.y;

  // staging: thread t -> LDS bytes [t*16, t*16+16); row = t/4, lds-unit = t%4.
  // XOR swizzle: data unit = (t%4) ^ ((row>>1)&3)  (breaks 8-way bank conflict)
  const int srow = tid >> 2;
  const int sunit = (tid & 3) ^ ((tid >> 3) & 3);
  long ar0 = (long)bm * 128 + srow;      if (ar0 > M - 1) ar0 = M - 1;
  long ar1 = (long)bm * 128 + srow + 64; if (ar1 > M - 1) ar1 = M - 1;
  long br0 = (long)bn * 128 + srow;      if (br0 > N - 1) br0 = N - 1;
  long br1 = (long)bn * 128 + srow + 64; if (br1 > N - 1) br1 = N - 1;
  const char* aSrc0 = (const char*)(A + ar0 * lda) + sunit * 16;
  const char* aSrc1 = (const char*)(A + ar1 * lda) + sunit * 16;
  const char* bSrc0 = (const char*)(B + br0 * ldb) + sunit * 16;
  const char* bSrc1 = (const char*)(B + br1 * ldb) + sunit * 16;
  char* ldsA0 = (char*)As + wave * 1024;
  char* ldsA1 = (char*)As + 4096 + wave * 1024;
  char* ldsB0 = (char*)Bs + wave * 1024;
  char* ldsB1 = (char*)Bs + 4096 + wave * 1024;

  const int r16 = lane & 15;
  const int kq = lane >> 4;  // 0..3, k-chunk of 8
  const int wm = wave & 1, wn = wave >> 1;

  int aoff[4], boff[4];
#pragma unroll
  for (int t = 0; t < 4; ++t) {
    int arow = wm * 64 + t * 16 + r16;
    aoff[t] = arow * 64 + ((kq ^ ((arow >> 1) & 3)) << 4);
    int brow = wn * 64 + t * 16 + r16;
    boff[t] = brow * 64 + ((kq ^ ((brow >> 1) & 3)) << 4);
  }

  f32x4 acc[4][4] = {};

  for (int k0 = 0; k0 < K; k0 += 32) {
    __syncthreads();
    size_t kb = (size_t)k0 * 2;
    gl_lds16(aSrc0 + kb, ldsA0);
    gl_lds16(aSrc1 + kb, ldsA1);
    gl_lds16(bSrc0 + kb, ldsB0);
    gl_lds16(bSrc1 + kb, ldsB1);
    __syncthreads();

    f16x8 af[4], bf[4];
#pragma unroll
    for (int t = 0; t < 4; ++t) {
      af[t] = *(const f16x8*)((const char*)As + aoff[t]);
      bf[t] = *(const f16x8*)((const char*)Bs + boff[t]);
    }
#pragma unroll
    for (int mt = 0; mt < 4; ++mt)
#pragma unroll
      for (int nt = 0; nt < 4; ++nt)
        acc[mt][nt] = __builtin_amdgcn_mfma_f32_16x16x32_f16(af[mt], bf[nt], acc[mt][nt], 0, 0, 0);
  }

  const int crow0 = bm * 128 + wm * 64;
  const int ccol0 = bn * 128 + wn * 64;
#pragma unroll
  for (int mt = 0; mt < 4; ++mt)
#pragma unroll
    for (int nt = 0; nt < 4; ++nt)
#pragma unroll
      for (int r = 0; r < 4; ++r) {
        int row = crow0 + mt * 16 + kq * 4 + r;
        int col = ccol0 + nt * 16 + r16;
        if (row < M && col < N)
          C[(size_t)row * ldc + col] = (f16)acc[mt][nt][r];
      }
}

// ---------- aggregation: out[n] = act( dinv[n]^2*h[n] + sum_e wn[e]*h[col[e]] + b ) ----------
template <typename OutT>
__global__ void agg_relu(const f16* __restrict__ h, int ldh,
                         const int* __restrict__ rowptr, const int* __restrict__ col,
                         const float* __restrict__ wn, const float* __restrict__ dinv,
                         const float* __restrict__ bias, OutT* __restrict__ out,
                         int ldo, int D) {
  const int node = blockIdx.x;
  const int d0 = threadIdx.x * 2;
  if (d0 < D) {
    const float dv = dinv[node];
    float a0, a1;
    {
      f16x2 v = *(const f16x2*)(h + (size_t)node * ldh + d0);
      float w0 = dv * dv;
      a0 = w0 * (float)v[0];
      a1 = w0 * (float)v[1];
    }
    int e = rowptr[node];
    const int end = rowptr[node + 1];
    for (; e < end; ++e) {
      int c = col[e];
      float w = wn[e];
      f16x2 v = *(const f16x2*)(h + (size_t)c * ldh + d0);
      a0 += w * (float)v[0];
      a1 += w * (float)v[1];
    }
    float o0 = fmaxf(a0 + bias[d0], 0.f);
    float o1 = fmaxf(a1 + bias[d0 + 1], 0.f);
    if constexpr (sizeof(OutT) == 2) {
      f16x2 o; o[0] = (f16)o0; o[1] = (f16)o1;
      *(f16x2*)((f16*)out + (size_t)node * ldo + d0) = o;
    } else {
      out[(size_t)node * ldo + d0] = o0;
      out[(size_t)node * ldo + d0 + 1] = o1;
    }
  } else if (d0 < ldo) {
    if constexpr (sizeof(OutT) == 2) {
      f16x2 o; o[0] = (f16)0.f; o[1] = (f16)0.f;
      *(f16x2*)((f16*)out + (size_t)node * ldo + d0) = o;
    }
  }
}

extern "C" void kernel_launch(void* const* d_in, const int* in_sizes, int n_in,
                              void* d_out, int out_size, void* d_ws, size_t ws_size,
                              hipStream_t stream) {
  const float* x  = (const float*)d_in[0];
  const float* W1 = (const float*)d_in[1];
  const float* b1 = (const float*)d_in[2];
  const float* W2 = (const float*)d_in[3];
  const float* b2 = (const float*)d_in[4];
  const float* W3 = (const float*)d_in[5];
  const float* b3 = (const float*)d_in[6];
  const int* eidx = (const int*)d_in[7];
  const int* esrc = eidx;
  const int* edst = eidx + N_EDGES;
  float* out = (float*)d_out;

  char* ws = (char*)d_ws;
  // region A (128 MB): xh for layer1, then reused for h2/g2/h3
  f16* xh = (f16*)(ws);                      // 50000*1280*2 = 128,000,000
  f16* h2 = (f16*)(ws);                      // 50000*300*2  =  30,000,000
  f16* g2 = (f16*)(ws + 32000000);           // 50000*320*2  =  32,000,000
  f16* h3 = (f16*)(ws + 66000000);           // 50000*300*2  =  30,000,000
  f16* h1 = (f16*)(ws + 128000000);          // 50000*512*2  =  51,200,000
  f16* g1 = (f16*)(ws + 179200000);          // 50000*512*2  =  51,200,000
  f16* w1h = (f16*)(ws + 230400000);         // 512*1280*2   =   1,310,720
  f16* w2h = (f16*)(ws + 231710720);         // 300*512*2    =     307,200
  f16* w3h = (f16*)(ws + 232017920);         // 300*320*2    =     192,000
  int* deg    = (int*)(ws + 232209920);      // 200,000
  float* dinv = (float*)(ws + 232409920);    // 200,000
  int* rowptr = (int*)(ws + 232609920);      // 200,004
  int* cursor = (int*)(ws + 232809924);      // 200,000
  int* col    = (int*)(ws + 233009924);      // 2,400,000
  float* wnorm = (float*)(ws + 235409924);   // 2,400,000  -> total 237,809,924 B

  hipMemsetAsync(deg, 0, N_NODES * sizeof(int), stream);
  hipMemsetAsync(cursor, 0, N_NODES * sizeof(int), stream);

  // conversions
  k_f32_to_f16_x4<<<62500, 256, 0, stream>>>(x, xh, 16000000L);  // 50000*1280/4
  k_wt<<<dim3(5, 512), 256, 0, stream>>>(W1, w1h, 1280, 512, 1280);
  k_wt<<<dim3(2, 300), 256, 0, stream>>>(W2, w2h, 512, 300, 512);
  k_wt<<<dim3(2, 300), 256, 0, stream>>>(W3, w3h, 300, 300, 320);

  // graph build
  k_deg<<<2344, 256, 0, stream>>>(edst, deg, N_EDGES);
  k_dinv<<<196, 256, 0, stream>>>(deg, dinv, N_NODES);
  k_scan<<<1, 1024, 0, stream>>>(deg, rowptr, N_NODES);
  k_fill<<<2344, 256, 0, stream>>>(esrc, edst, rowptr, cursor, col, wnorm, dinv, N_EDGES);

  // layer 1: h1 = xh @ W1 ; g1 = relu(agg(h1) + b1)
  gemm_f16_tn<<<dim3(391, 4), 256, 0, stream>>>(xh, w1h, h1, N_NODES, 512, 1280, 1280, 1280, 512);
  agg_relu<f16><<<N_NODES, 256, 0, stream>>>(h1, 512, rowptr, col, wnorm, dinv, b1, g1, 512, 512);

  // layer 2: h2 = g1 @ W2 ; g2 = relu(agg(h2) + b2), K-padded to 320
  gemm_f16_tn<<<dim3(391, 3), 256, 0, stream>>>(g1, w2h, h2, N_NODES, 300, 512, 512, 512, 300);
  agg_relu<f16><<<N_NODES, 256, 0, stream>>>(h2, 300, rowptr, col, wnorm, dinv, b2, g2, 320, 300);

  // layer 3: h3 = g2 @ W3 ; out = relu(agg(h3) + b3)  (fp32 out)
  gemm_f16_tn<<<dim3(391, 3), 256, 0, stream>>>(g2, w3h, h3, N_NODES, 300, 320, 320, 320, 300);
  agg_relu<float><<<N_NODES, 256, 0, stream>>>(h3, 300, rowptr, col, wnorm, dinv, b3, out, 300, 300);
}

// Round 2
// 887.875 us; speedup vs baseline: 1.1987x; 1.1987x over previous
//
#include <hip/hip_runtime.h>

typedef _Float16 f16;
typedef _Float16 f16x2 __attribute__((ext_vector_type(2)));
typedef _Float16 f16x4 __attribute__((ext_vector_type(4)));
typedef _Float16 f16x8 __attribute__((ext_vector_type(8)));
typedef float f32x4 __attribute__((ext_vector_type(4)));

#define N_NODES 50000
#define N_EDGES 600000

// ---------- async global->LDS, 16B per lane ----------
__device__ __forceinline__ void gl_lds16(const void* g, void* l) {
  __builtin_amdgcn_global_load_lds(
      (__attribute__((address_space(1))) void*)(g),
      (__attribute__((address_space(3))) void*)(l), 16, 0, 0);
}

// ---------- conversions ----------
__global__ void k_f32_to_f16_x4(const float* __restrict__ in, f16* __restrict__ out, long n4) {
  long i = (long)blockIdx.x * 256 + threadIdx.x;
  if (i < n4) {
    float4 v = ((const float4*)in)[i];
    f16x4 o;
    o[0] = (f16)v.x; o[1] = (f16)v.y; o[2] = (f16)v.z; o[3] = (f16)v.w;
    ((f16x4*)out)[i] = o;
  }
}

// Wt[n][k] = W[k][n] (f16), zero-pad k in [K, Kpad)
__global__ void k_wt(const float* __restrict__ W, f16* __restrict__ Wt,
                     int K, int N, int Kpad) {
  int k = blockIdx.x * 256 + threadIdx.x;
  int n = blockIdx.y;
  if (k < Kpad)
    Wt[(size_t)n * Kpad + k] = (k < K) ? (f16)W[(size_t)k * N + n] : (f16)0.f;
}

// pad a fp32 vector with zeros up to blockDim.x
__global__ void k_padvec(const float* __restrict__ a, float* __restrict__ out, int n) {
  int t = threadIdx.x;
  out[t] = (t < n) ? a[t] : 0.f;
}

// ---------- graph build ----------
__global__ void k_deg(const int* __restrict__ dst, int* __restrict__ deg, int E) {
  int e = blockIdx.x * 256 + threadIdx.x;
  if (e < E) atomicAdd(&deg[dst[e]], 1);
}

__global__ void k_dinv(const int* __restrict__ deg, float* __restrict__ dinv, int n) {
  int i = blockIdx.x * 256 + threadIdx.x;
  if (i < n) dinv[i] = rsqrtf((float)(deg[i] + 1));  // +1 self loop
}

// exclusive scan of deg -> rowptr[0..n], single block of 1024
__global__ void k_scan(const int* __restrict__ deg, int* __restrict__ rowptr, int n) {
  __shared__ int wsum[16];
  __shared__ int carry_s;
  int tid = threadIdx.x;
  int lane = tid & 63, w = tid >> 6;
  if (tid == 0) carry_s = 0;
  __syncthreads();
  for (int base = 0; base < n; base += 1024) {
    int i = base + tid;
    int v = (i < n) ? deg[i] : 0;
    int incl = v;
#pragma unroll
    for (int off = 1; off < 64; off <<= 1) {
      int t = __shfl_up(incl, off, 64);
      if (lane >= off) incl += t;
    }
    if (lane == 63) wsum[w] = incl;
    __syncthreads();
    if (tid < 16) {
      int t = wsum[tid];
#pragma unroll
      for (int off = 1; off < 16; off <<= 1) {
        int u = __shfl_up(t, off, 64);
        if (tid >= off) t += u;
      }
      wsum[tid] = t;  // inclusive over waves
    }
    __syncthreads();
    int c = carry_s;
    int wprefix = (w == 0) ? 0 : wsum[w - 1];
    if (i < n) rowptr[i] = c + wprefix + incl - v;
    __syncthreads();
    if (tid == 0) carry_s = c + wsum[15];
    __syncthreads();
  }
  if (threadIdx.x == 0) rowptr[n] = carry_s;
}

// fill CSR: meta[pos] = {src, bitcast(norm)}
__global__ void k_fill(const int* __restrict__ src, const int* __restrict__ dst,
                       const int* __restrict__ rowptr, int* __restrict__ cursor,
                       int2* __restrict__ meta, const float* __restrict__ dinv, int E) {
  int e = blockIdx.x * 256 + threadIdx.x;
  if (e < E) {
    int d = dst[e], s = src[e];
    int pos = rowptr[d] + atomicAdd(&cursor[d], 1);
    float w = dinv[s] * dinv[d];
    meta[pos] = make_int2(s, __float_as_int(w));
  }
}

// ---------- GEMM: C[M,N] = A[M,K] * B^T[N,K], f16 in, f16 out ----------
// 128x128 tile, BK=32, 4 waves (2x2 of 64x64), mfma_f32_16x16x32_f16
// zero-fills C cols in [N, ldc)
__global__ __launch_bounds__(256, 2)
void gemm_f16_tn(const f16* __restrict__ A, const f16* __restrict__ B,
                 f16* __restrict__ C, int M, int N, int K,
                 int lda, int ldb, int ldc) {
  __shared__ __align__(16) f16 As[128 * 32];
  __shared__ __align__(16) f16 Bs[128 * 32];
  const int tid = threadIdx.x;
  const int wave = tid >> 6;
  const int lane = tid & 63;
  const int bm = blockIdx.x, bn = blockIdx.y;

  const int srow = tid >> 2;
  const int sunit = (tid & 3) ^ ((tid >> 3) & 3);
  long ar0 = (long)bm * 128 + srow;      if (ar0 > M - 1) ar0 = M - 1;
  long ar1 = (long)bm * 128 + srow + 64; if (ar1 > M - 1) ar1 = M - 1;
  long br0 = (long)bn * 128 + srow;      if (br0 > N - 1) br0 = N - 1;
  long br1 = (long)bn * 128 + srow + 64; if (br1 > N - 1) br1 = N - 1;
  const char* aSrc0 = (const char*)(A + ar0 * lda) + sunit * 16;
  const char* aSrc1 = (const char*)(A + ar1 * lda) + sunit * 16;
  const char* bSrc0 = (const char*)(B + br0 * ldb) + sunit * 16;
  const char* bSrc1 = (const char*)(B + br1 * ldb) + sunit * 16;
  char* ldsA0 = (char*)As + wave * 1024;
  char* ldsA1 = (char*)As + 4096 + wave * 1024;
  char* ldsB0 = (char*)Bs + wave * 1024;
  char* ldsB1 = (char*)Bs + 4096 + wave * 1024;

  const int r16 = lane & 15;
  const int kq = lane >> 4;  // 0..3, k-chunk of 8
  const int wm = wave & 1, wn = wave >> 1;

  int aoff[4], boff[4];
#pragma unroll
  for (int t = 0; t < 4; ++t) {
    int arow = wm * 64 + t * 16 + r16;
    aoff[t] = arow * 64 + ((kq ^ ((arow >> 1) & 3)) << 4);
    int brow = wn * 64 + t * 16 + r16;
    boff[t] = brow * 64 + ((kq ^ ((brow >> 1) & 3)) << 4);
  }

  f32x4 acc[4][4] = {};

  for (int k0 = 0; k0 < K; k0 += 32) {
    __syncthreads();
    size_t kb = (size_t)k0 * 2;
    gl_lds16(aSrc0 + kb, ldsA0);
    gl_lds16(aSrc1 + kb, ldsA1);
    gl_lds16(bSrc0 + kb, ldsB0);
    gl_lds16(bSrc1 + kb, ldsB1);
    __syncthreads();

    f16x8 af[4], bf[4];
#pragma unroll
    for (int t = 0; t < 4; ++t) {
      af[t] = *(const f16x8*)((const char*)As + aoff[t]);
      bf[t] = *(const f16x8*)((const char*)Bs + boff[t]);
    }
#pragma unroll
    for (int mt = 0; mt < 4; ++mt)
#pragma unroll
      for (int nt = 0; nt < 4; ++nt)
        acc[mt][nt] = __builtin_amdgcn_mfma_f32_16x16x32_f16(af[mt], bf[nt], acc[mt][nt], 0, 0, 0);
  }

  const int crow0 = bm * 128 + wm * 64;
  const int ccol0 = bn * 128 + wn * 64;
#pragma unroll
  for (int mt = 0; mt < 4; ++mt)
#pragma unroll
    for (int nt = 0; nt < 4; ++nt)
#pragma unroll
      for (int r = 0; r < 4; ++r) {
        int row = crow0 + mt * 16 + kq * 4 + r;
        int col = ccol0 + nt * 16 + r16;
        if (row < M && col < ldc)
          C[(size_t)row * ldc + col] = (col < N) ? (f16)acc[mt][nt][r] : (f16)0.f;
      }
}

// ---------- aggregation v2: wave-per-node, 16B/lane gather ----------
// out[n] = relu( dinv[n]^2*h[n] + sum_e w[e]*h[src[e]] + b )
template <int LDH, int ACT, bool F16OUT, int DOUT>
__global__ __launch_bounds__(256, 8)
void agg_relu2(const f16* __restrict__ h, const int* __restrict__ rowptr,
               const int2* __restrict__ meta, const float* __restrict__ dinv,
               const float* __restrict__ bias, void* __restrict__ outp, int nNodes) {
  const int tid = threadIdx.x;
  const int lane = tid & 63;
  const int node = blockIdx.x * 4 + (tid >> 6);
  if (node >= nNodes || lane >= ACT) return;
  const int un = __builtin_amdgcn_readfirstlane(node);
  const int r0 = __builtin_amdgcn_readfirstlane(rowptr[un]);
  const int r1 = __builtin_amdgcn_readfirstlane(rowptr[un + 1]);
  const float dv = __builtin_bit_cast(
      float, __builtin_amdgcn_readfirstlane(__builtin_bit_cast(int, dinv[un])));

  float acc[8];
  {
    f16x8 v = *(const f16x8*)(h + (size_t)un * LDH + lane * 8);
    const float w0 = dv * dv;
#pragma unroll
    for (int j = 0; j < 8; ++j) acc[j] = w0 * (float)v[j];
  }
  for (int e = r0; e < r1; ++e) {
    const int eu = __builtin_amdgcn_readfirstlane(e);
    int2 m = meta[eu];
    const float w = __builtin_bit_cast(float, m.y);
    f16x8 v = *(const f16x8*)(h + (size_t)m.x * LDH + lane * 8);
#pragma unroll
    for (int j = 0; j < 8; ++j) acc[j] = fmaf(w, (float)v[j], acc[j]);
  }

  float4 bv0 = *(const float4*)(bias + lane * 8);
  float4 bv1 = *(const float4*)(bias + lane * 8 + 4);
  float o[8];
  o[0] = fmaxf(acc[0] + bv0.x, 0.f); o[1] = fmaxf(acc[1] + bv0.y, 0.f);
  o[2] = fmaxf(acc[2] + bv0.z, 0.f); o[3] = fmaxf(acc[3] + bv0.w, 0.f);
  o[4] = fmaxf(acc[4] + bv1.x, 0.f); o[5] = fmaxf(acc[5] + bv1.y, 0.f);
  o[6] = fmaxf(acc[6] + bv1.z, 0.f); o[7] = fmaxf(acc[7] + bv1.w, 0.f);

  if constexpr (F16OUT) {
    f16x8 ov;
#pragma unroll
    for (int j = 0; j < 8; ++j) ov[j] = (f16)o[j];
    *(f16x8*)((f16*)outp + (size_t)un * LDH + lane * 8) = ov;
  } else {
    float* orow = (float*)outp + (size_t)un * DOUT + lane * 8;
    float4 s0 = make_float4(o[0], o[1], o[2], o[3]);
    float4 s1 = make_float4(o[4], o[5], o[6], o[7]);
    if (lane * 8 + 4 <= DOUT) *(float4*)(orow) = s0;
    if (lane * 8 + 8 <= DOUT) *(float4*)(orow + 4) = s1;
  }
}

extern "C" void kernel_launch(void* const* d_in, const int* in_sizes, int n_in,
                              void* d_out, int out_size, void* d_ws, size_t ws_size,
                              hipStream_t stream) {
  const float* x  = (const float*)d_in[0];
  const float* W1 = (const float*)d_in[1];
  const float* b1 = (const float*)d_in[2];
  const float* W2 = (const float*)d_in[3];
  const float* b2 = (const float*)d_in[4];
  const float* W3 = (const float*)d_in[5];
  const float* b3 = (const float*)d_in[6];
  const int* eidx = (const int*)d_in[7];
  const int* esrc = eidx;
  const int* edst = eidx + N_EDGES;
  float* out = (float*)d_out;

  char* ws = (char*)d_ws;
  f16* xh = (f16*)(ws);                      // 50000*1280*2 = 128,000,000
  f16* h2 = (f16*)(ws);                      // 50000*320*2  =  32,000,000
  f16* g2 = (f16*)(ws + 32000000);           // 50000*320*2  =  32,000,000
  f16* h3 = (f16*)(ws + 64000000);           // 50000*320*2  =  32,000,000
  f16* h1 = (f16*)(ws + 128000000);          // 50000*512*2  =  51,200,000
  f16* g1 = (f16*)(ws + 179200000);          // 50000*512*2  =  51,200,000
  f16* w1h = (f16*)(ws + 230400000);         // 512*1280*2   =   1,310,720
  f16* w2h = (f16*)(ws + 231710720);         // 300*512*2    =     307,200
  f16* w3h = (f16*)(ws + 232017920);         // 300*320*2    =     192,000
  float* bp2 = (float*)(ws + 232209920);     // 320*4 = 1,280
  float* bp3 = (float*)(ws + 232211200);     // 1,280
  int* deg    = (int*)(ws + 232212480);      // 200,000
  float* dinv = (float*)(ws + 232412480);    // 200,000
  int* rowptr = (int*)(ws + 232612480);      // 200,004
  int* cursor = (int*)(ws + 232812488);      // 200,000
  int2* meta  = (int2*)(ws + 233012488);     // 600000*8 = 4,800,000 -> total 237,812,488

  hipMemsetAsync(deg, 0, N_NODES * sizeof(int), stream);
  hipMemsetAsync(cursor, 0, N_NODES * sizeof(int), stream);

  // conversions
  k_f32_to_f16_x4<<<62500, 256, 0, stream>>>(x, xh, 16000000L);  // 50000*1280/4
  k_wt<<<dim3(5, 512), 256, 0, stream>>>(W1, w1h, 1280, 512, 1280);
  k_wt<<<dim3(2, 300), 256, 0, stream>>>(W2, w2h, 512, 300, 512);
  k_wt<<<dim3(2, 300), 256, 0, stream>>>(W3, w3h, 300, 300, 320);
  k_padvec<<<1, 320, 0, stream>>>(b2, bp2, 300);
  k_padvec<<<1, 320, 0, stream>>>(b3, bp3, 300);

  // graph build
  k_deg<<<2344, 256, 0, stream>>>(edst, deg, N_EDGES);
  k_dinv<<<196, 256, 0, stream>>>(deg, dinv, N_NODES);
  k_scan<<<1, 1024, 0, stream>>>(deg, rowptr, N_NODES);
  k_fill<<<2344, 256, 0, stream>>>(esrc, edst, rowptr, cursor, meta, dinv, N_EDGES);

  // layer 1: h1 = xh @ W1 ; g1 = relu(agg(h1) + b1)
  gemm_f16_tn<<<dim3(391, 4), 256, 0, stream>>>(xh, w1h, h1, N_NODES, 512, 1280, 1280, 1280, 512);
  agg_relu2<512, 64, true, 0><<<12500, 256, 0, stream>>>(h1, rowptr, meta, dinv, b1, g1, N_NODES);

  // layer 2: h2 = g1 @ W2 (ldc=320, pad zeroed) ; g2 = relu(agg(h2) + bp2)
  gemm_f16_tn<<<dim3(391, 3), 256, 0, stream>>>(g1, w2h, h2, N_NODES, 300, 512, 512, 512, 320);
  agg_relu2<320, 40, true, 0><<<12500, 256, 0, stream>>>(h2, rowptr, meta, dinv, bp2, g2, N_NODES);

  // layer 3: h3 = g2 @ W3 (K=320 padded) ; out = relu(agg(h3) + bp3) fp32
  gemm_f16_tn<<<dim3(391, 3), 256, 0, stream>>>(g2, w3h, h3, N_NODES, 300, 320, 320, 320, 320);
  agg_relu2<320, 38, false, 300><<<12500, 256, 0, stream>>>(h3, rowptr, meta, dinv, bp3, out, N_NODES);
}

// Round 3
// 814.094 us; speedup vs baseline: 1.3073x; 1.0906x over previous
//
#include <hip/hip_runtime.h>

typedef _Float16 f16;
typedef _Float16 f16x2 __attribute__((ext_vector_type(2)));
typedef _Float16 f16x4 __attribute__((ext_vector_type(4)));
typedef _Float16 f16x8 __attribute__((ext_vector_type(8)));
typedef float f32x4 __attribute__((ext_vector_type(4)));

#define N_NODES 50000
#define N_EDGES 600000

// ---------- async global->LDS, 16B per lane ----------
__device__ __forceinline__ void gl_lds16(const void* g, void* l) {
  __builtin_amdgcn_global_load_lds(
      (__attribute__((address_space(1))) void*)(g),
      (__attribute__((address_space(3))) void*)(l), 16, 0, 0);
}

// ---------- merged setup: x->f16, deg atomics, W transposes, bias pads ----------
// grid layout (blocks of 256):
//   [0, 62500)        x convert (50000*1280/4 float4s, exact)
//   [62500, 64844)    deg atomics over 600000 edges
//   [64844, 67404)    W1^T  (655360 elems, exact)
//   [67404, 68004)    W2^T  (300 rows x 2 blocks)
//   [68004, 68604)    W3^T padded to 320 (300 rows x 2 blocks)
//   [68604, 68606)    bp2
//   [68606, 68608)    bp3
__global__ void k_setup(const float* __restrict__ x, f16* __restrict__ xh,
                        const float* __restrict__ W1, f16* __restrict__ w1h,
                        const float* __restrict__ W2, f16* __restrict__ w2h,
                        const float* __restrict__ W3, f16* __restrict__ w3h,
                        const float* __restrict__ b2, float* __restrict__ bp2,
                        const float* __restrict__ b3, float* __restrict__ bp3,
                        const int* __restrict__ edst, int* __restrict__ deg) {
  const int b = blockIdx.x, t = threadIdx.x;
  if (b < 62500) {
    long i = (long)b * 256 + t;
    float4 v = ((const float4*)x)[i];
    f16x4 o;
    o[0] = (f16)v.x; o[1] = (f16)v.y; o[2] = (f16)v.z; o[3] = (f16)v.w;
    ((f16x4*)xh)[i] = o;
  } else if (b < 64844) {
    int e = (b - 62500) * 256 + t;
    if (e < N_EDGES) atomicAdd(&deg[edst[e]], 1);
  } else if (b < 67404) {
    int idx = (b - 64844) * 256 + t;       // = n*1280 + k
    int n = idx / 1280, k = idx - n * 1280;
    w1h[idx] = (f16)W1[(size_t)k * 512 + n];
  } else if (b < 68004) {
    int bb = b - 67404;
    int n = bb >> 1, k = (bb & 1) * 256 + t;
    if (k < 512) w2h[(size_t)n * 512 + k] = (f16)W2[(size_t)k * 300 + n];
  } else if (b < 68604) {
    int bb = b - 68004;
    int n = bb >> 1, k = (bb & 1) * 256 + t;
    if (k < 320) w3h[(size_t)n * 320 + k] = (k < 300) ? (f16)W3[(size_t)k * 300 + n] : (f16)0.f;
  } else if (b < 68606) {
    int i = (b - 68604) * 256 + t;
    if (i < 320) bp2[i] = (i < 300) ? b2[i] : 0.f;
  } else {
    int i = (b - 68606) * 256 + t;
    if (i < 320) bp3[i] = (i < 300) ? b3[i] : 0.f;
  }
}

// ---------- multi-block exclusive scan of deg -> rowptr ----------
__device__ __forceinline__ int block_incl_scan256(int v, int t) {
  __shared__ int wsum[4];
  const int lane = t & 63, w = t >> 6;
  int incl = v;
#pragma unroll
  for (int off = 1; off < 64; off <<= 1) {
    int u = __shfl_up(incl, off, 64);
    if (lane >= off) incl += u;
  }
  if (lane == 63) wsum[w] = incl;
  __syncthreads();
  int add = 0;
#pragma unroll
  for (int k = 0; k < 4; ++k)
    if (k < w) add += wsum[k];
  return incl + add;
}

// per-block sums + dinv
__global__ void k_scan1(const int* __restrict__ deg, float* __restrict__ dinv,
                        int* __restrict__ bsum, int n) {
  __shared__ int ws4[4];
  const int t = threadIdx.x, b = blockIdx.x;
  const int i = b * 256 + t;
  int v = (i < n) ? deg[i] : 0;
  if (i < n) dinv[i] = rsqrtf((float)(v + 1));
  int s = v;
#pragma unroll
  for (int off = 1; off < 64; off <<= 1) s += __shfl_xor(s, off, 64);
  if ((t & 63) == 0) ws4[t >> 6] = s;
  __syncthreads();
  if (t == 0) bsum[b] = ws4[0] + ws4[1] + ws4[2] + ws4[3];
}

// scan the 196 block sums (single tiny block) + total -> rowptr[n]
__global__ void k_scan2(const int* __restrict__ bsum, int* __restrict__ bpre,
                        int* __restrict__ rowptr, int nb, int n) {
  const int t = threadIdx.x;
  int v = (t < nb) ? bsum[t] : 0;
  int incl = block_incl_scan256(v, t);
  if (t < nb) bpre[t] = incl - v;
  if (t == 255) rowptr[n] = incl;
}

// full exclusive positions; write rowptr and a second copy used as atomic cursor
__global__ void k_scan3(const int* __restrict__ deg, const int* __restrict__ bpre,
                        int* __restrict__ rowptr, int* __restrict__ rptr2, int n) {
  const int t = threadIdx.x, b = blockIdx.x;
  const int i = b * 256 + t;
  int v = (i < n) ? deg[i] : 0;
  int incl = block_incl_scan256(v, t);
  int ex = bpre[b] + incl - v;
  if (i < n) { rowptr[i] = ex; rptr2[i] = ex; }
}

// fill CSR: meta[pos] = {src, bitcast(norm)}; rptr2 doubles as cursor
__global__ void k_fill(const int* __restrict__ src, const int* __restrict__ dst,
                       int* __restrict__ rptr2, int2* __restrict__ meta,
                       const float* __restrict__ dinv, int E) {
  int e = blockIdx.x * 256 + threadIdx.x;
  if (e < E) {
    int d = dst[e], s = src[e];
    int pos = atomicAdd(&rptr2[d], 1);
    float w = dinv[s] * dinv[d];
    meta[pos] = make_int2(s, __float_as_int(w));
  }
}

// ---------- GEMM: C[M,N] = A[M,K] * B^T[N,K], f16 in, f16 out ----------
// 128x128 tile, BK=32, 4 waves (2x2 of 64x64), mfma_f32_16x16x32_f16
// zero-fills C cols in [N, ldc)
__global__ __launch_bounds__(256, 2)
void gemm_f16_tn(const f16* __restrict__ A, const f16* __restrict__ B,
                 f16* __restrict__ C, int M, int N, int K,
                 int lda, int ldb, int ldc) {
  __shared__ __align__(16) f16 As[128 * 32];
  __shared__ __align__(16) f16 Bs[128 * 32];
  const int tid = threadIdx.x;
  const int wave = tid >> 6;
  const int lane = tid & 63;
  const int bm = blockIdx.x, bn = blockIdx.y;

  const int srow = tid >> 2;
  const int sunit = (tid & 3) ^ ((tid >> 3) & 3);
  long ar0 = (long)bm * 128 + srow;      if (ar0 > M - 1) ar0 = M - 1;
  long ar1 = (long)bm * 128 + srow + 64; if (ar1 > M - 1) ar1 = M - 1;
  long br0 = (long)bn * 128 + srow;      if (br0 > N - 1) br0 = N - 1;
  long br1 = (long)bn * 128 + srow + 64; if (br1 > N - 1) br1 = N - 1;
  const char* aSrc0 = (const char*)(A + ar0 * lda) + sunit * 16;
  const char* aSrc1 = (const char*)(A + ar1 * lda) + sunit * 16;
  const char* bSrc0 = (const char*)(B + br0 * ldb) + sunit * 16;
  const char* bSrc1 = (const char*)(B + br1 * ldb) + sunit * 16;
  char* ldsA0 = (char*)As + wave * 1024;
  char* ldsA1 = (char*)As + 4096 + wave * 1024;
  char* ldsB0 = (char*)Bs + wave * 1024;
  char* ldsB1 = (char*)Bs + 4096 + wave * 1024;

  const int r16 = lane & 15;
  const int kq = lane >> 4;  // 0..3, k-chunk of 8
  const int wm = wave & 1, wn = wave >> 1;

  int aoff[4], boff[4];
#pragma unroll
  for (int t = 0; t < 4; ++t) {
    int arow = wm * 64 + t * 16 + r16;
    aoff[t] = arow * 64 + ((kq ^ ((arow >> 1) & 3)) << 4);
    int brow = wn * 64 + t * 16 + r16;
    boff[t] = brow * 64 + ((kq ^ ((brow >> 1) & 3)) << 4);
  }

  f32x4 acc[4][4] = {};

  for (int k0 = 0; k0 < K; k0 += 32) {
    __syncthreads();
    size_t kb = (size_t)k0 * 2;
    gl_lds16(aSrc0 + kb, ldsA0);
    gl_lds16(aSrc1 + kb, ldsA1);
    gl_lds16(bSrc0 + kb, ldsB0);
    gl_lds16(bSrc1 + kb, ldsB1);
    __syncthreads();

    f16x8 af[4], bf[4];
#pragma unroll
    for (int t = 0; t < 4; ++t) {
      af[t] = *(const f16x8*)((const char*)As + aoff[t]);
      bf[t] = *(const f16x8*)((const char*)Bs + boff[t]);
    }
#pragma unroll
    for (int mt = 0; mt < 4; ++mt)
#pragma unroll
      for (int nt = 0; nt < 4; ++nt)
        acc[mt][nt] = __builtin_amdgcn_mfma_f32_16x16x32_f16(af[mt], bf[nt], acc[mt][nt], 0, 0, 0);
  }

  const int crow0 = bm * 128 + wm * 64;
  const int ccol0 = bn * 128 + wn * 64;
#pragma unroll
  for (int mt = 0; mt < 4; ++mt)
#pragma unroll
    for (int nt = 0; nt < 4; ++nt)
#pragma unroll
      for (int r = 0; r < 4; ++r) {
        int row = crow0 + mt * 16 + kq * 4 + r;
        int col = ccol0 + nt * 16 + r16;
        if (row < M && col < ldc)
          C[(size_t)row * ldc + col] = (col < N) ? (f16)acc[mt][nt][r] : (f16)0.f;
      }
}

// ---------- aggregation v3: wave-per-node, coalesced meta prefetch + shuffle bcast ----------
// out[n] = relu( dinv[n]^2*h[n] + sum_e w[e]*h[src[e]] + b )
template <int LDH, int ACT, bool F16OUT, int DOUT>
__global__ __launch_bounds__(256, 8)
void agg_relu3(const f16* __restrict__ h, const int* __restrict__ rowptr,
               const int2* __restrict__ meta, const float* __restrict__ dinv,
               const float* __restrict__ bias, void* __restrict__ outp, int nNodes) {
  const int tid = threadIdx.x;
  const int lane = tid & 63;
  const int node = blockIdx.x * 4 + (tid >> 6);
  if (node >= nNodes) return;
  const int r0 = __builtin_amdgcn_readfirstlane(rowptr[node]);
  const int r1 = __builtin_amdgcn_readfirstlane(rowptr[node + 1]);
  const float dv = __builtin_bit_cast(
      float, __builtin_amdgcn_readfirstlane(__builtin_bit_cast(int, dinv[node])));

  // idle lanes (>= ACT) read a duplicate 16B (coalesces away) so the whole
  // wave stays alive for the meta prefetch.
  const int hoff = (lane < ACT ? lane : ACT - 1) * 8;
  const f16* hp = h + hoff;

  float acc[8];
  {
    f16x8 v = *(const f16x8*)(hp + (size_t)node * LDH);
    const float w0 = dv * dv;
#pragma unroll
    for (int j = 0; j < 8; ++j) acc[j] = w0 * (float)v[j];
  }

  for (int base = r0; base < r1; base += 64) {
    const int idx = base + lane;
    int2 m = (idx < r1) ? meta[idx] : make_int2(0, 0);
    const int cnt = min(64, r1 - base);
    int j = 0;
    for (; j + 2 <= cnt; j += 2) {
      int s0 = __shfl(m.x, j, 64);
      int s1 = __shfl(m.x, j + 1, 64);
      float w0 = __int_as_float(__shfl(m.y, j, 64));
      float w1 = __int_as_float(__shfl(m.y, j + 1, 64));
      f16x8 v0 = *(const f16x8*)(hp + (size_t)s0 * LDH);
      f16x8 v1 = *(const f16x8*)(hp + (size_t)s1 * LDH);
#pragma unroll
      for (int q = 0; q < 8; ++q) acc[q] = fmaf(w0, (float)v0[q], acc[q]);
#pragma unroll
      for (int q = 0; q < 8; ++q) acc[q] = fmaf(w1, (float)v1[q], acc[q]);
    }
    if (j < cnt) {
      int s0 = __shfl(m.x, j, 64);
      float w0 = __int_as_float(__shfl(m.y, j, 64));
      f16x8 v0 = *(const f16x8*)(hp + (size_t)s0 * LDH);
#pragma unroll
      for (int q = 0; q < 8; ++q) acc[q] = fmaf(w0, (float)v0[q], acc[q]);
    }
  }

  float4 bv0 = *(const float4*)(bias + hoff);
  float4 bv1 = *(const float4*)(bias + hoff + 4);
  float o[8];
  o[0] = fmaxf(acc[0] + bv0.x, 0.f); o[1] = fmaxf(acc[1] + bv0.y, 0.f);
  o[2] = fmaxf(acc[2] + bv0.z, 0.f); o[3] = fmaxf(acc[3] + bv0.w, 0.f);
  o[4] = fmaxf(acc[4] + bv1.x, 0.f); o[5] = fmaxf(acc[5] + bv1.y, 0.f);
  o[6] = fmaxf(acc[6] + bv1.z, 0.f); o[7] = fmaxf(acc[7] + bv1.w, 0.f);

  if constexpr (F16OUT) {
    if (lane < ACT) {
      f16x8 ov;
#pragma unroll
      for (int j = 0; j < 8; ++j) ov[j] = (f16)o[j];
      *(f16x8*)((f16*)outp + (size_t)node * LDH + lane * 8) = ov;
    }
  } else {
    float* orow = (float*)outp + (size_t)node * DOUT + lane * 8;
    if (lane * 8 + 4 <= DOUT)
      *(float4*)(orow) = make_float4(o[0], o[1], o[2], o[3]);
    if (lane * 8 + 8 <= DOUT)
      *(float4*)(orow + 4) = make_float4(o[4], o[5], o[6], o[7]);
  }
}

extern "C" void kernel_launch(void* const* d_in, const int* in_sizes, int n_in,
                              void* d_out, int out_size, void* d_ws, size_t ws_size,
                              hipStream_t stream) {
  const float* x  = (const float*)d_in[0];
  const float* W1 = (const float*)d_in[1];
  const float* b1 = (const float*)d_in[2];
  const float* W2 = (const float*)d_in[3];
  const float* b2 = (const float*)d_in[4];
  const float* W3 = (const float*)d_in[5];
  const float* b3 = (const float*)d_in[6];
  const int* eidx = (const int*)d_in[7];
  const int* esrc = eidx;
  const int* edst = eidx + N_EDGES;
  float* out = (float*)d_out;

  char* ws = (char*)d_ws;
  f16* xh = (f16*)(ws);                      // 50000*1280*2 = 128,000,000
  f16* h2 = (f16*)(ws);                      // 50000*320*2  =  32,000,000
  f16* g2 = (f16*)(ws + 32000000);           // 32,000,000
  f16* h3 = (f16*)(ws + 64000000);           // 32,000,000
  f16* h1 = (f16*)(ws + 128000000);          // 50000*512*2  =  51,200,000
  f16* g1 = (f16*)(ws + 179200000);          // 51,200,000
  f16* w1h = (f16*)(ws + 230400000);         // 1,310,720
  f16* w2h = (f16*)(ws + 231710720);         //   307,200
  f16* w3h = (f16*)(ws + 232017920);         //   192,000
  float* bp2 = (float*)(ws + 232209920);     //     1,280
  float* bp3 = (float*)(ws + 232211200);     //     1,280
  int* deg    = (int*)(ws + 232212480);      //   200,000
  float* dinv = (float*)(ws + 232412480);    //   200,000
  int* rowptr = (int*)(ws + 232612480);      //   200,004
  int* rptr2  = (int*)(ws + 232812484);      //   200,004
  int* bsum   = (int*)(ws + 233012488);      //       800
  int* bpre   = (int*)(ws + 233013288);      //       800
  int2* meta  = (int2*)(ws + 233014088);     // 4,800,000 -> total 237,814,088

  hipMemsetAsync(deg, 0, N_NODES * sizeof(int), stream);

  // merged setup: x convert + deg atomics + W^T + bias pads
  k_setup<<<68608, 256, 0, stream>>>(x, xh, W1, w1h, W2, w2h, W3, w3h,
                                     b2, bp2, b3, bp3, edst, deg);

  // multi-block scan + dinv
  k_scan1<<<196, 256, 0, stream>>>(deg, dinv, bsum, N_NODES);
  k_scan2<<<1, 256, 0, stream>>>(bsum, bpre, rowptr, 196, N_NODES);
  k_scan3<<<196, 256, 0, stream>>>(deg, bpre, rowptr, rptr2, N_NODES);
  k_fill<<<2344, 256, 0, stream>>>(esrc, edst, rptr2, meta, dinv, N_EDGES);

  // layer 1: h1 = xh @ W1 ; g1 = relu(agg(h1) + b1)
  gemm_f16_tn<<<dim3(391, 4), 256, 0, stream>>>(xh, w1h, h1, N_NODES, 512, 1280, 1280, 1280, 512);
  agg_relu3<512, 64, true, 0><<<12500, 256, 0, stream>>>(h1, rowptr, meta, dinv, b1, g1, N_NODES);

  // layer 2: h2 = g1 @ W2 (ldc=320, pad zeroed) ; g2 = relu(agg(h2) + bp2)
  gemm_f16_tn<<<dim3(391, 3), 256, 0, stream>>>(g1, w2h, h2, N_NODES, 300, 512, 512, 512, 320);
  agg_relu3<320, 40, true, 0><<<12500, 256, 0, stream>>>(h2, rowptr, meta, dinv, bp2, g2, N_NODES);

  // layer 3: h3 = g2 @ W3 (K=320 padded) ; out = relu(agg(h3) + bp3) fp32
  gemm_f16_tn<<<dim3(391, 3), 256, 0, stream>>>(g2, w3h, h3, N_NODES, 300, 320, 320, 320, 320);
  agg_relu3<320, 38, false, 300><<<12500, 256, 0, stream>>>(h3, rowptr, meta, dinv, bp3, out, N_NODES);
}